// Round 15
// baseline (1097.212 us; speedup 1.0000x reference)
//
#include <hip/hip_runtime.h>

typedef unsigned short u16;
typedef unsigned int u32;
typedef unsigned long long u64;
typedef __attribute__((ext_vector_type(8))) short short8;
typedef __attribute__((ext_vector_type(4))) float f32x4;
typedef __attribute__((ext_vector_type(4))) unsigned int u32x4;

#define B_ 64
#define T_ 1024
#define D2_ 512
#define HD_ 256
#define G4_ 1024
#define PD_ 100
#define KX_ 640
#define KO_ 768
#define LBL_ 96
#define LPAD_ 128

__device__ __forceinline__ float bf2f(u16 u) {
  u32 v = ((u32)u) << 16;
  return __builtin_bit_cast(float, v);
}
__device__ __forceinline__ u16 f2bf(float f) {
  u32 u = __builtin_bit_cast(u32, f);
  u32 r = (u + 0x7fffu + ((u >> 16) & 1u)) >> 16;
  return (u16)r;
}
__device__ __forceinline__ u32 pk2(float a, float b) {
  return (u32)f2bf(a) | ((u32)f2bf(b) << 16);
}
__device__ __forceinline__ float sgm(float x) {
  return __builtin_amdgcn_rcpf(1.f + __builtin_amdgcn_exp2f(-1.442695040888963f * x));
}
__device__ __forceinline__ float thh(float x) {
  return fmaf(-2.f,
              __builtin_amdgcn_rcpf(1.f + __builtin_amdgcn_exp2f(2.885390081777927f * x)),
              1.f);
}
// fp4 e2m1 encode of pre-scaled y (values {0,.5,1,1.5,2,3,4,6}), round-nearest
__device__ __forceinline__ u32 enc4(float y) {
  float a = fabsf(y);
  u32 c = 0;
  c = a >= 0.25f ? 1u : c;
  c = a >= 0.75f ? 2u : c;
  c = a >= 1.25f ? 3u : c;
  c = a >= 1.75f ? 4u : c;
  c = a >= 2.5f ? 5u : c;
  c = a >= 3.5f ? 6u : c;
  c = a >= 5.0f ? 7u : c;
  return c | ((__builtin_bit_cast(u32, y) >> 28) & 8u);
}
// Native-width fp4 MFMA, B and C/D in AGPRs, A from VGPR (fresh LDS read).
// Bit-exact vs rounds 13/14 (absmax signature 0.3125).
__device__ __forceinline__ f32x4 mfma4_init(u32x4 a, u32x4 b, f32x4 c) {
  f32x4 d;
  asm volatile("v_mfma_f32_16x16x128_f8f6f4 %0, %1, %2, %3 cbsz:4 blgp:4"
               : "=&a"(d)
               : "v"(a), "a"(b), "a"(c));
  return d;
}
__device__ __forceinline__ void mfma4_acc(f32x4& d, u32x4 a, u32x4 b) {
  asm volatile("v_mfma_f32_16x16x128_f8f6f4 %0, %1, %2, %0 cbsz:4 blgp:4"
               : "+a"(d)
               : "v"(a), "a"(b));
}

// ---------------- K0: weight prep ----------------
// wc: comb_W bf16 [256][640] padded; wih: W_ih bf16; w4: W_hh fp4 e2m1
// nibbles [1024][128B] (w*8); wlin: lin_W bf16 [128][768]; biasg = b_ih + b_hh
__global__ __launch_bounds__(256) void k_prep(
    const float* combW, const float* Wih, const float* bih, const float* Whh,
    const float* bhh, const float* linW, u16* wc, u16* wih, u32* w4, u16* wlin,
    float* biasg) {
  int idx = blockIdx.x * 256 + threadIdx.x;
  if (idx < 256 * KX_) {
    int r = idx / KX_, c = idx % KX_;
    wc[idx] = f2bf(c < 612 ? combW[r * 612 + c] : 0.f);
    return;
  }
  idx -= 256 * KX_;
  if (idx < G4_ * HD_) { wih[idx] = f2bf(Wih[idx]); return; }
  idx -= G4_ * HD_;
  if (idx < G4_ * HD_ / 8) {  // 8 weights -> 1 u32 of nibbles (elem k at nibble k)
    int n = idx >> 5, c0 = (idx & 31) * 8;
    const float* wr = Whh + n * 256 + c0;
    u32 word = 0;
#pragma unroll
    for (int i = 0; i < 4; ++i) {
      u32 byte = enc4(wr[2 * i] * 8.f) | (enc4(wr[2 * i + 1] * 8.f) << 4);
      word |= byte << (8 * i);
    }
    w4[n * 32 + (c0 >> 3)] = word;
    return;
  }
  idx -= G4_ * HD_ / 8;
  if (idx < LPAD_ * KO_) {
    int r = idx / KO_;
    wlin[idx] = f2bf(r < LBL_ ? linW[idx] : 0.f);
    return;
  }
  idx -= LPAD_ * KO_;
  if (idx < G4_) biasg[idx] = bih[idx] + bhh[idx];
}

// ---------------- K1a: chunk sums S[b*16+c][d] = sum_{j<64} enc[b][c*64+j][d]
__global__ __launch_bounds__(512) void k_psum(const float* enc, float* S) {
  const int bc = blockIdx.x;  // b*16 + c
  const int d = threadIdx.x;
  const int b = bc >> 4, c = bc & 15;
  const float* e = enc + (((size_t)b * T_) + c * 64) * D2_ + d;
  float s = 0.f;
#pragma unroll 8
  for (int j = 0; j < 64; ++j) s += e[(size_t)j * D2_];
  S[(size_t)bc * D2_ + d] = s;
}

// ---------------- K1b: P[b][c*64+j][d] = chunk_offset + local exclusive scan
__global__ __launch_bounds__(512) void k_pwrite(const float* enc, const float* S,
                                                float* P) {
  const int bc = blockIdx.x;
  const int d = threadIdx.x;
  const int b = bc >> 4, c = bc & 15;
  float off = 0.f;
  for (int c2 = 0; c2 < c; ++c2) off += S[((size_t)(b * 16 + c2)) * D2_ + d];
  const float* e = enc + (((size_t)b * T_) + c * 64) * D2_ + d;
  float* p = P + (((size_t)b * T_) + c * 64) * D2_ + d;
#pragma unroll 4
  for (int j = 0; j < 64; ++j) {
    p[(size_t)j * D2_] = off;
    off += e[(size_t)j * D2_];
  }
}

// ---------------- K2: X rows [pe(100) | avg(512) | pad(28)] bf16 -------------
__global__ __launch_bounds__(320) void k_xbuild(const float* P, const float* ptab,
                                                const int* pid, const int* sidx,
                                                u16* X) {
  const int tid = threadIdx.x;
  const int row = tid / 80;
  const int ir = tid - row * 80;
  const int m = blockIdx.x * 4 + row;  // m = t*64 + b
  const int t = m >> 6, b = m & 63;
  int pp = 0, ps = 0;
  if (t > 0) {
    pp = pid[(t - 1) * B_ + b];
    ps = sidx[(t - 1) * B_ + b];
  }
  bool valid = (ps >= 0) && (t > 0);
  int start = min(ps, t - 1);
  start = max(start, 0);
  start = min(start, T_ - 1);
  float invlen = 1.f / (float)max(t - start, 1);
  const float* Pt = P + ((size_t)b * T_ + t) * D2_;
  const float* Ps = P + ((size_t)b * T_ + start) * D2_;
  const int k0 = ir * 8;
  uint4 o;
  if (k0 >= 104 && k0 + 8 <= 612) {  // pure avg zone, 16B-aligned float4s
    if (valid) {
      int d = k0 - 100;
      float4 t0 = *(const float4*)(Pt + d), t1 = *(const float4*)(Pt + d + 4);
      float4 s0 = *(const float4*)(Ps + d), s1 = *(const float4*)(Ps + d + 4);
      o.x = pk2((t0.x - s0.x) * invlen, (t0.y - s0.y) * invlen);
      o.y = pk2((t0.z - s0.z) * invlen, (t0.w - s0.w) * invlen);
      o.z = pk2((t1.x - s1.x) * invlen, (t1.y - s1.y) * invlen);
      o.w = pk2((t1.z - s1.z) * invlen, (t1.w - s1.w) * invlen);
    } else {
      o = (uint4){0, 0, 0, 0};
    }
  } else if (k0 + 8 <= 100) {  // pure pos-table zone
    const float* pr = ptab + pp * PD_ + k0;
    o.x = pk2(pr[0], pr[1]);
    o.y = pk2(pr[2], pr[3]);
    o.z = pk2(pr[4], pr[5]);
    o.w = pk2(pr[6], pr[7]);
  } else if (k0 >= 616) {
    o = (uint4){0, 0, 0, 0};
  } else {  // mixed boundary chunks (ir == 12 or 76)
    u32 ow[4];
#pragma unroll
    for (int j2 = 0; j2 < 4; ++j2) {
      float v[2];
#pragma unroll
      for (int jj = 0; jj < 2; ++jj) {
        int k = k0 + j2 * 2 + jj;
        float x;
        if (k < PD_) x = ptab[pp * PD_ + k];
        else if (k < 612) x = valid ? (Pt[k - PD_] - Ps[k - PD_]) * invlen : 0.f;
        else x = 0.f;
        v[jj] = x;
      }
      ow[j2] = pk2(v[0], v[1]);
    }
    o = (uint4){ow[0], ow[1], ow[2], ow[3]};
  }
  *(uint4*)(X + (size_t)m * KX_ + k0) = o;
}

// ---------------- 128x128-tile bf16 MFMA GEMM: out = A @ Bw^T ----------------
// MODE 0: Z = tanh(X@Wc^T + comb_b), zero rows m<64, bf16 out, N=256, K=640
// MODE 1: G = Z@Wih^T + biasg -> layout G[m][cell*4+gate], N=1024, K=256
template <int MODE>
__global__ __launch_bounds__(256, 2) void k_gemm(const u16* A, const u16* Bw,
                                                 const float* bias, u16* outb) {
  constexpr int K = (MODE == 0) ? KX_ : HD_;
  constexpr int NOUT = (MODE == 0) ? 256 : 1024;
  __shared__ u16 As[128][40];
  __shared__ u16 Bs[128][40];
  const int m0 = blockIdx.x * 128, n0 = blockIdx.y * 128;
  const int tid = threadIdx.x;
  const int w = tid >> 6, l = tid & 63;
  const int wr = w >> 1, wc = w & 1;
  const int l15 = l & 15, lh = l >> 4;
  const int srow = tid >> 2, sc8 = (tid & 3) * 8;
  int brow0, brow1;
  if constexpr (MODE == 1) {
    int j0 = n0 + srow, j1 = n0 + srow + 64;
    brow0 = (j0 & 3) * 256 + (j0 >> 2);
    brow1 = (j1 & 3) * 256 + (j1 >> 2);
  } else {
    brow0 = n0 + srow;
    brow1 = n0 + srow + 64;
  }
  f32x4 acc[4][4] = {};
  for (int k0 = 0; k0 < K; k0 += 32) {
    uint4 a0 = *(const uint4*)(A + (size_t)(m0 + srow) * K + k0 + sc8);
    uint4 a1 = *(const uint4*)(A + (size_t)(m0 + srow + 64) * K + k0 + sc8);
    uint4 b0 = *(const uint4*)(Bw + (size_t)brow0 * K + k0 + sc8);
    uint4 b1 = *(const uint4*)(Bw + (size_t)brow1 * K + k0 + sc8);
    __syncthreads();  // previous iter's LDS reads complete
    *(uint4*)&As[srow][sc8] = a0;
    *(uint4*)&As[srow + 64][sc8] = a1;
    *(uint4*)&Bs[srow][sc8] = b0;
    *(uint4*)&Bs[srow + 64][sc8] = b1;
    __syncthreads();
    short8 af[4], bf[4];
#pragma unroll
    for (int i = 0; i < 4; ++i) {
      af[i] = *(const short8*)&As[wr * 64 + i * 16 + l15][lh * 8];
      bf[i] = *(const short8*)&Bs[wc * 64 + i * 16 + l15][lh * 8];
    }
#pragma unroll
    for (int mi = 0; mi < 4; ++mi)
#pragma unroll
      for (int ni = 0; ni < 4; ++ni)
        acc[mi][ni] =
            __builtin_amdgcn_mfma_f32_16x16x32_bf16(af[mi], bf[ni], acc[mi][ni], 0, 0, 0);
  }
#pragma unroll
  for (int mi = 0; mi < 4; ++mi)
#pragma unroll
    for (int ni = 0; ni < 4; ++ni)
#pragma unroll
      for (int r = 0; r < 4; ++r) {
        int gm = m0 + wr * 64 + mi * 16 + lh * 4 + r;
        int gn = n0 + wc * 64 + ni * 16 + l15;
        float v = acc[mi][ni][r];
        if constexpr (MODE == 0) {
          v = tanhf(v + bias[gn]);
          if (gm < 64) v = 0.f;  // t == 0 rows
          outb[(size_t)gm * NOUT + gn] = f2bf(v);
        } else {
          v += bias[(gn & 3) * 256 + (gn >> 2)];
          outb[(size_t)gm * NOUT + gn] = f2bf(v);
        }
      }
}

// ---------------- K5: sequential LSTM, fp4 MFMA, 16-wave (4 waves/SIMD) ------
// 1024 threads. Wave w owns cells [w*16, w*16+16): 4 gates x 2 K-blocks =
// 8 MFMA/wave/step (block total 128, unchanged). 4 waves/SIMD overlap the
// ~700-cy per-step serial chain (barrier -> ds_read -> MFMA -> trans tail)
// that 2 waves/SIMD could not hide (r9/r13/r14 step-time invariance).
// Per-wave readout halves: 4 accs, no hi-select. Regs/wave ~108 < 128 cap.
__global__ __launch_bounds__(1024, 4) void k_seq(const u16* G, const u32* w4,
                                                 u16* Hout) {
  __shared__ __align__(16) unsigned char hq[2][128];
  const int b = blockIdx.x;
  const int tid = threadIdx.x;
  const int w = tid >> 6, l = tid & 63;
  const int c16 = l & 15, quad = l >> 4;
  const unsigned char* w4b = (const unsigned char*)w4;
  const int mycell = w * 16 + c16;
  u32x4 Bf[4][2];
#pragma unroll
  for (int g = 0; g < 4; ++g) {
    int n = g * 256 + mycell;
#pragma unroll
    for (int kb = 0; kb < 2; ++kb)
      Bf[g][kb] = *(const u32x4*)(w4b + (size_t)n * 128 + kb * 64 + quad * 16);
  }
  f32x4 Z4 = (f32x4){0.f, 0.f, 0.f, 0.f};
  asm volatile("" : "+a"(Z4));  // zero C-operand, AGPR-resident once
  if (tid < 128) hq[0][tid] = 0;
  const u16* gptr = G + (size_t)b * 1024 + mycell * 4;
  u64 gq = *(const u64*)gptr;
  float cc = 0.f;
  int cur = 0;
  __syncthreads();
  for (int t = 0; t < T_; ++t) {
    int tn = (t + 1 < T_) ? t + 1 : t;
    u64 ngq = *(const u64*)(gptr + (size_t)tn * 65536);
    u32x4 a0 = *(const u32x4*)&hq[cur][quad * 16];       // kb=0: k 0..127
    u32x4 a1 = *(const u32x4*)&hq[cur][64 + quad * 16];  // kb=1: k 128..255
    f32x4 acc[4];
#pragma unroll
    for (int g = 0; g < 4; ++g) acc[g] = mfma4_init(a0, Bf[g][0], Z4);
#pragma unroll
    for (int g = 0; g < 4; ++g) mfma4_acc(acc[g], a1, Bf[g][1]);
    __builtin_amdgcn_sched_barrier(0);
    asm volatile("s_nop 7\n\ts_nop 7\n\ts_nop 7");  // MFMA -> read fence
    float vi = fmaf(acc[0][0], 0.03125f, bf2f((u16)gq));
    float vf = fmaf(acc[1][0], 0.03125f, bf2f((u16)(gq >> 16)));
    float vg = fmaf(acc[2][0], 0.03125f, bf2f((u16)(gq >> 32)));
    float vo = fmaf(acc[3][0], 0.03125f, bf2f((u16)(gq >> 48)));
    cc = sgm(vf) * cc + sgm(vi) * thh(vg);
    float h = sgm(vo) * thh(cc);
    u32 nib = enc4(h * 4.f);                  // h scale 2^-2
    u32 nib2 = (u32)__shfl_xor((int)nib, 1);  // neighbor cell's nibble
    if (quad == 0) {
      if ((c16 & 1) == 0)
        hq[cur ^ 1][mycell >> 1] = (unsigned char)(nib | (nib2 << 4));
      Hout[((size_t)b * 1024 + t) * 256 + mycell] = f2bf(h);
    }
    gq = ngq;
    cur ^= 1;
    __syncthreads();
  }
}

// ---------------- K6: fused output GEMM + log-softmax ------------------------
__global__ __launch_bounds__(256) void k_out(const u16* Hs, const float* enc,
                                             const u16* wlin, float* out) {
  __shared__ u16 As[64][40];
  __shared__ u16 Bs[128][40];
  const int m0 = blockIdx.x * 64;
  const int tid = threadIdx.x;
  const int srow = tid >> 2, sc8 = (tid & 3) * 8;
  const int brow = tid >> 1, bc16 = (tid & 1) * 16;
  const int w = tid >> 6, l = tid & 63;
  const int l15 = l & 15, lh = l >> 4;
  f32x4 acc[8] = {};
  for (int k0 = 0; k0 < KO_; k0 += 32) {
    int k = k0 + sc8;
    uint4 av;
    if (k < 256) {
      av = *(const uint4*)(Hs + (size_t)(m0 + srow) * 256 + k);
    } else {
      const float* src = enc + (size_t)(m0 + srow) * 512 + (k - 256);
      float4 f0 = *(const float4*)(src);
      float4 f1 = *(const float4*)(src + 4);
      av.x = pk2(f0.x, f0.y);
      av.y = pk2(f0.z, f0.w);
      av.z = pk2(f1.x, f1.y);
      av.w = pk2(f1.z, f1.w);
    }
    *(uint4*)&As[srow][sc8] = av;
    const u16* bsrc = wlin + (size_t)brow * KO_ + k0 + bc16;
    *(uint4*)&Bs[brow][bc16] = *(const uint4*)(bsrc);
    *(uint4*)&Bs[brow][bc16 + 8] = *(const uint4*)(bsrc + 8);
    __syncthreads();
    short8 a8 = *(const short8*)&As[16 * w + l15][lh * 8];
#pragma unroll
    for (int nt = 0; nt < 8; ++nt) {
      short8 b8 = *(const short8*)&Bs[nt * 16 + l15][lh * 8];
      acc[nt] = __builtin_amdgcn_mfma_f32_16x16x32_bf16(a8, b8, acc[nt], 0, 0, 0);
    }
    __syncthreads();
  }
#pragma unroll
  for (int r = 0; r < 4; ++r) {
    int gm = m0 + 16 * w + lh * 4 + r;
    float v[8];
#pragma unroll
    for (int nt = 0; nt < 8; ++nt) v[nt] = acc[nt][r];
    if ((gm & (T_ - 1)) == 0 && l15 == 1) v[0] = -1e10f;  // t==0, col==APP_ID
    float mx = v[0];
#pragma unroll
    for (int nt = 1; nt < 6; ++nt) mx = fmaxf(mx, v[nt]);
#pragma unroll
    for (int s = 1; s < 16; s <<= 1) mx = fmaxf(mx, __shfl_xor(mx, s));
    float s0 = 0.f;
#pragma unroll
    for (int nt = 0; nt < 6; ++nt)
      s0 += __builtin_amdgcn_exp2f(1.442695040888963f * (v[nt] - mx));
#pragma unroll
    for (int s = 1; s < 16; s <<= 1) s0 += __shfl_xor(s0, s);
    float lg = __builtin_amdgcn_logf(s0) * 0.6931471805599453f + mx;
#pragma unroll
    for (int nt = 0; nt < 6; ++nt)
      out[(size_t)gm * LBL_ + nt * 16 + l15] = v[nt] - lg;
  }
}

extern "C" void kernel_launch(void* const* d_in, const int* in_sizes, int n_in,
                              void* d_out, int out_size, void* d_ws, size_t ws_size,
                              hipStream_t stream) {
  const float* enc = (const float*)d_in[0];
  const float* ptab = (const float*)d_in[1];
  const float* Wih = (const float*)d_in[2];
  const float* bih = (const float*)d_in[3];
  const float* Whh = (const float*)d_in[4];
  const float* bhh = (const float*)d_in[5];
  const float* combW = (const float*)d_in[6];
  const float* combb = (const float*)d_in[7];
  const float* linW = (const float*)d_in[8];
  const int* pid = (const int*)d_in[9];
  const int* sidx = (const int*)d_in[10];

  char* ws = (char*)d_ws;
  size_t off = 0;
  auto alloc = [&](size_t bytes) {
    void* p = ws + off;
    off += (bytes + 255) & ~(size_t)255;
    return p;
  };
  float* P = (float*)alloc((size_t)B_ * T_ * D2_ * 4);  // -> aliased by G
  u16* Xb = (u16*)alloc((size_t)T_ * B_ * KX_ * 2);     // -> aliased by H
  u16* Z = (u16*)alloc((size_t)T_ * B_ * HD_ * 2);      // S (2MB) lives here first
  u16* wc = (u16*)alloc(256 * KX_ * 2);
  u16* wih = (u16*)alloc(G4_ * HD_ * 2);
  u32* w4 = (u32*)alloc(G4_ * HD_ / 2);  // fp4 nibbles: 1024 x 128 B
  u16* wlin = (u16*)alloc(LPAD_ * KO_ * 2);
  float* biasg = (float*)alloc(G4_ * 4);
  u16* G = (u16*)P;
  u16* Hs = (u16*)Xb;
  float* S = (float*)Z;  // 1024*512 f32 = 2MB, dead before Z is written
  float* out = (float*)d_out;

  k_prep<<<2180, 256, 0, stream>>>(combW, Wih, bih, Whh, bhh, linW, wc, wih, w4,
                                   wlin, biasg);
  k_psum<<<B_ * 16, 512, 0, stream>>>(enc, S);
  k_pwrite<<<B_ * 16, 512, 0, stream>>>(enc, S, P);
  k_xbuild<<<T_ * B_ / 4, 320, 0, stream>>>(P, ptab, pid, sidx, Xb);
  dim3 g3(512, 2);
  k_gemm<0><<<g3, 256, 0, stream>>>(Xb, wc, combb, Z);
  dim3 g4(512, 8);
  k_gemm<1><<<g4, 256, 0, stream>>>(Z, wih, biasg, G);
  k_seq<<<B_, 1024, 0, stream>>>(G, w4, Hs);
  k_out<<<1024, 256, 0, stream>>>(Hs, enc, wlin, out);
}

// Round 16
// 869.963 us; speedup vs baseline: 1.2612x; 1.2612x over previous
//
#include <hip/hip_runtime.h>

typedef unsigned short u16;
typedef unsigned int u32;
typedef unsigned long long u64;
typedef __attribute__((ext_vector_type(8))) short short8;
typedef __attribute__((ext_vector_type(4))) float f32x4;
typedef __attribute__((ext_vector_type(8))) int i32x8;

#define B_ 64
#define T_ 1024
#define D2_ 512
#define HD_ 256
#define G4_ 1024
#define PD_ 100
#define KX_ 640
#define KO_ 768
#define LBL_ 96
#define LPAD_ 128
// e8m0 scale bytes: A stored = h*4 -> 2^-2 (125); B stored = w*8 -> 2^-3 (124)
#define SCA 125
#define SCB 124

__device__ __forceinline__ float bf2f(u16 u) {
  u32 v = ((u32)u) << 16;
  return __builtin_bit_cast(float, v);
}
__device__ __forceinline__ u16 f2bf(float f) {
  u32 u = __builtin_bit_cast(u32, f);
  u32 r = (u + 0x7fffu + ((u >> 16) & 1u)) >> 16;
  return (u16)r;
}
__device__ __forceinline__ u32 pk2(float a, float b) {
  return (u32)f2bf(a) | ((u32)f2bf(b) << 16);
}
__device__ __forceinline__ float sgm(float x) {
  return __builtin_amdgcn_rcpf(1.f + __builtin_amdgcn_exp2f(-1.442695040888963f * x));
}
__device__ __forceinline__ float thh(float x) {
  return fmaf(-2.f,
              __builtin_amdgcn_rcpf(1.f + __builtin_amdgcn_exp2f(2.885390081777927f * x)),
              1.f);
}
// fp4 e2m1 encode of pre-scaled y (values {0,.5,1,1.5,2,3,4,6}), round-nearest
__device__ __forceinline__ u32 enc4(float y) {
  float a = fabsf(y);
  u32 c = 0;
  c = a >= 0.25f ? 1u : c;
  c = a >= 0.75f ? 2u : c;
  c = a >= 1.25f ? 3u : c;
  c = a >= 1.75f ? 4u : c;
  c = a >= 2.5f ? 5u : c;
  c = a >= 3.5f ? 6u : c;
  c = a >= 5.0f ? 7u : c;
  return c | ((__builtin_bit_cast(u32, y) >> 28) & 8u);
}

// ---------------- K0: weight prep ----------------
// wc: comb_W bf16 [256][640] padded; wih: W_ih bf16; w4: W_hh fp4 e2m1
// nibbles [1024][128B] (w*8); wlin: lin_W bf16 [128][768]; biasg = b_ih + b_hh
__global__ __launch_bounds__(256) void k_prep(
    const float* combW, const float* Wih, const float* bih, const float* Whh,
    const float* bhh, const float* linW, u16* wc, u16* wih, u32* w4, u16* wlin,
    float* biasg) {
  int idx = blockIdx.x * 256 + threadIdx.x;
  if (idx < 256 * KX_) {
    int r = idx / KX_, c = idx % KX_;
    wc[idx] = f2bf(c < 612 ? combW[r * 612 + c] : 0.f);
    return;
  }
  idx -= 256 * KX_;
  if (idx < G4_ * HD_) { wih[idx] = f2bf(Wih[idx]); return; }
  idx -= G4_ * HD_;
  if (idx < G4_ * HD_ / 8) {  // 8 weights -> 1 u32 of nibbles (elem k at nibble k)
    int n = idx >> 5, c0 = (idx & 31) * 8;
    const float* wr = Whh + n * 256 + c0;
    u32 word = 0;
#pragma unroll
    for (int i = 0; i < 4; ++i) {
      u32 byte = enc4(wr[2 * i] * 8.f) | (enc4(wr[2 * i + 1] * 8.f) << 4);
      word |= byte << (8 * i);
    }
    w4[n * 32 + (c0 >> 3)] = word;
    return;
  }
  idx -= G4_ * HD_ / 8;
  if (idx < LPAD_ * KO_) {
    int r = idx / KO_;
    wlin[idx] = f2bf(r < LBL_ ? linW[idx] : 0.f);
    return;
  }
  idx -= LPAD_ * KO_;
  if (idx < G4_) biasg[idx] = bih[idx] + bhh[idx];
}

// ---------------- K1a: chunk sums S[b*16+c][d] = sum_{j<64} enc[b][c*64+j][d]
__global__ __launch_bounds__(512) void k_psum(const float* enc, float* S) {
  const int bc = blockIdx.x;  // b*16 + c
  const int d = threadIdx.x;
  const int b = bc >> 4, c = bc & 15;
  const float* e = enc + (((size_t)b * T_) + c * 64) * D2_ + d;
  float s = 0.f;
#pragma unroll 8
  for (int j = 0; j < 64; ++j) s += e[(size_t)j * D2_];
  S[(size_t)bc * D2_ + d] = s;
}

// ---------------- K1b: Pb (bf16) = chunk_offset + local exclusive scan -------
__global__ __launch_bounds__(512) void k_pwrite(const float* enc, const float* S,
                                                u16* Pb) {
  const int bc = blockIdx.x;
  const int d = threadIdx.x;
  const int b = bc >> 4, c = bc & 15;
  float off = 0.f;
  for (int c2 = 0; c2 < c; ++c2) off += S[((size_t)(b * 16 + c2)) * D2_ + d];
  const float* e = enc + (((size_t)b * T_) + c * 64) * D2_ + d;
  u16* p = Pb + (((size_t)b * T_) + c * 64) * D2_ + d;
#pragma unroll 4
  for (int j = 0; j < 64; ++j) {
    p[(size_t)j * D2_] = f2bf(off);
    off += e[(size_t)j * D2_];
  }
}

// ---------------- K2: X rows [pe(100) | avg(512) | pad(28)] bf16 -------------
// P is bf16 now: avg zone reads 2x ushort4 per operand (8B-aligned, d%4==0).
__global__ __launch_bounds__(320) void k_xbuild(const u16* Pb, const float* ptab,
                                                const int* pid, const int* sidx,
                                                u16* X) {
  const int tid = threadIdx.x;
  const int row = tid / 80;
  const int ir = tid - row * 80;
  const int m = blockIdx.x * 4 + row;  // m = t*64 + b
  const int t = m >> 6, b = m & 63;
  int pp = 0, ps = 0;
  if (t > 0) {
    pp = pid[(t - 1) * B_ + b];
    ps = sidx[(t - 1) * B_ + b];
  }
  bool valid = (ps >= 0) && (t > 0);
  int start = min(ps, t - 1);
  start = max(start, 0);
  start = min(start, T_ - 1);
  float invlen = 1.f / (float)max(t - start, 1);
  const u16* Pt = Pb + ((size_t)b * T_ + t) * D2_;
  const u16* Ps = Pb + ((size_t)b * T_ + start) * D2_;
  const int k0 = ir * 8;
  uint4 o;
  if (k0 >= 104 && k0 + 8 <= 612) {  // pure avg zone
    if (valid) {
      int d = k0 - 100;
      ushort4 ta = *(const ushort4*)(Pt + d);
      ushort4 tb = *(const ushort4*)(Pt + d + 4);
      ushort4 sa = *(const ushort4*)(Ps + d);
      ushort4 sb = *(const ushort4*)(Ps + d + 4);
      o.x = pk2((bf2f(ta.x) - bf2f(sa.x)) * invlen,
                (bf2f(ta.y) - bf2f(sa.y)) * invlen);
      o.y = pk2((bf2f(ta.z) - bf2f(sa.z)) * invlen,
                (bf2f(ta.w) - bf2f(sa.w)) * invlen);
      o.z = pk2((bf2f(tb.x) - bf2f(sb.x)) * invlen,
                (bf2f(tb.y) - bf2f(sb.y)) * invlen);
      o.w = pk2((bf2f(tb.z) - bf2f(sb.z)) * invlen,
                (bf2f(tb.w) - bf2f(sb.w)) * invlen);
    } else {
      o = (uint4){0, 0, 0, 0};
    }
  } else if (k0 + 8 <= 100) {  // pure pos-table zone
    const float* pr = ptab + pp * PD_ + k0;
    o.x = pk2(pr[0], pr[1]);
    o.y = pk2(pr[2], pr[3]);
    o.z = pk2(pr[4], pr[5]);
    o.w = pk2(pr[6], pr[7]);
  } else if (k0 >= 616) {
    o = (uint4){0, 0, 0, 0};
  } else {  // mixed boundary chunks (ir == 12 or 76)
    u32 ow[4];
#pragma unroll
    for (int j2 = 0; j2 < 4; ++j2) {
      float v[2];
#pragma unroll
      for (int jj = 0; jj < 2; ++jj) {
        int k = k0 + j2 * 2 + jj;
        float x;
        if (k < PD_) x = ptab[pp * PD_ + k];
        else if (k < 612)
          x = valid ? (bf2f(Pt[k - PD_]) - bf2f(Ps[k - PD_])) * invlen : 0.f;
        else x = 0.f;
        v[jj] = x;
      }
      ow[j2] = pk2(v[0], v[1]);
    }
    o = (uint4){ow[0], ow[1], ow[2], ow[3]};
  }
  *(uint4*)(X + (size_t)m * KX_ + k0) = o;
}

// ---------------- 128x128-tile bf16 MFMA GEMM: out = A @ Bw^T ----------------
// Grid: (n_tiles, m_tiles) — consecutive blocks share the A-panel (L2/L3 reuse).
// MODE 0: Z = tanh(X@Wc^T + comb_b), zero rows m<64, bf16 out, N=256, K=640
// MODE 1: G = Z@Wih^T + biasg -> layout G[m][cell*4+gate], N=1024, K=256
template <int MODE>
__global__ __launch_bounds__(256, 2) void k_gemm(const u16* A, const u16* Bw,
                                                 const float* bias, u16* outb) {
  constexpr int K = (MODE == 0) ? KX_ : HD_;
  constexpr int NOUT = (MODE == 0) ? 256 : 1024;
  __shared__ u16 As[128][40];
  __shared__ u16 Bs[128][40];
  const int m0 = blockIdx.y * 128, n0 = blockIdx.x * 128;
  const int tid = threadIdx.x;
  const int w = tid >> 6, l = tid & 63;
  const int wr = w >> 1, wc = w & 1;
  const int l15 = l & 15, lh = l >> 4;
  const int srow = tid >> 2, sc8 = (tid & 3) * 8;
  int brow0, brow1;
  if constexpr (MODE == 1) {
    int j0 = n0 + srow, j1 = n0 + srow + 64;
    brow0 = (j0 & 3) * 256 + (j0 >> 2);
    brow1 = (j1 & 3) * 256 + (j1 >> 2);
  } else {
    brow0 = n0 + srow;
    brow1 = n0 + srow + 64;
  }
  f32x4 acc[4][4] = {};
  for (int k0 = 0; k0 < K; k0 += 32) {
    uint4 a0 = *(const uint4*)(A + (size_t)(m0 + srow) * K + k0 + sc8);
    uint4 a1 = *(const uint4*)(A + (size_t)(m0 + srow + 64) * K + k0 + sc8);
    uint4 b0 = *(const uint4*)(Bw + (size_t)brow0 * K + k0 + sc8);
    uint4 b1 = *(const uint4*)(Bw + (size_t)brow1 * K + k0 + sc8);
    __syncthreads();  // previous iter's LDS reads complete
    *(uint4*)&As[srow][sc8] = a0;
    *(uint4*)&As[srow + 64][sc8] = a1;
    *(uint4*)&Bs[srow][sc8] = b0;
    *(uint4*)&Bs[srow + 64][sc8] = b1;
    __syncthreads();
    short8 af[4], bf[4];
#pragma unroll
    for (int i = 0; i < 4; ++i) {
      af[i] = *(const short8*)&As[wr * 64 + i * 16 + l15][lh * 8];
      bf[i] = *(const short8*)&Bs[wc * 64 + i * 16 + l15][lh * 8];
    }
#pragma unroll
    for (int mi = 0; mi < 4; ++mi)
#pragma unroll
      for (int ni = 0; ni < 4; ++ni)
        acc[mi][ni] =
            __builtin_amdgcn_mfma_f32_16x16x32_bf16(af[mi], bf[ni], acc[mi][ni], 0, 0, 0);
  }
#pragma unroll
  for (int mi = 0; mi < 4; ++mi)
#pragma unroll
    for (int ni = 0; ni < 4; ++ni)
#pragma unroll
      for (int r = 0; r < 4; ++r) {
        int gm = m0 + wr * 64 + mi * 16 + lh * 4 + r;
        int gn = n0 + wc * 64 + ni * 16 + l15;
        float v = acc[mi][ni][r];
        if constexpr (MODE == 0) {
          v = tanhf(v + bias[gn]);
          if (gm < 64) v = 0.f;  // t == 0 rows
          outb[(size_t)gm * NOUT + gn] = f2bf(v);
        } else {
          v += bias[(gn & 3) * 256 + (gn >> 2)];
          outb[(size_t)gm * NOUT + gn] = f2bf(v);
        }
      }
}

// ---------------- K5: sequential LSTM via MX fp4 MFMA (round-9 champion) -----
// 8 waves. Wave w owns cells [w*32, w*32+32): 2ct x 4g x 2kb B-frags as fp4
// nibbles (uint4). acc re-zeroed every step; gate = dot + G-bias at readout.
// One cell per thread (quads 0-1 -> ct0, quads 2-3 -> ct1). 597 us measured.
__global__ __launch_bounds__(512, 2) void k_seq(const u16* G, const u32* w4,
                                                u16* Hout) {
  __shared__ __align__(16) unsigned char hq[2][128];
  const int b = blockIdx.x;
  const int tid = threadIdx.x;
  const int w = tid >> 6, l = tid & 63;
  const int c16 = l & 15, quad = l >> 4;
  const unsigned char* w4b = (const unsigned char*)w4;
  uint4 Bf[2][4][2];
#pragma unroll
  for (int ct = 0; ct < 2; ++ct)
#pragma unroll
    for (int g = 0; g < 4; ++g) {
      int n = g * 256 + w * 32 + ct * 16 + c16;
#pragma unroll
      for (int kb = 0; kb < 2; ++kb)
        Bf[ct][g][kb] = *(const uint4*)(w4b + (size_t)n * 128 + kb * 64 + quad * 16);
    }
  if (tid < 128) hq[0][tid] = 0;
  const int myct = quad >> 1;
  const int mycell = w * 32 + myct * 16 + c16;
  const u16* gptr = G + (size_t)b * 1024 + mycell * 4;
  u64 gq = *(const u64*)gptr;
  float cc = 0.f;
  int cur = 0;
  __syncthreads();
  for (int t = 0; t < T_; ++t) {
    int tn = (t + 1 < T_) ? t + 1 : t;
    u64 ngq = *(const u64*)(gptr + (size_t)tn * 65536);
    uint4 a0 = *(const uint4*)&hq[cur][quad * 16];       // kb=0: k 0..127
    uint4 a1 = *(const uint4*)&hq[cur][64 + quad * 16];  // kb=1: k 128..255
    i32x8 A0 = (i32x8){(int)a0.x, (int)a0.y, (int)a0.z, (int)a0.w, 0, 0, 0, 0};
    i32x8 A1 = (i32x8){(int)a1.x, (int)a1.y, (int)a1.z, (int)a1.w, 0, 0, 0, 0};
    f32x4 acc[2][4];
#pragma unroll
    for (int ct = 0; ct < 2; ++ct)
#pragma unroll
      for (int g = 0; g < 4; ++g) {
        uint4 b0 = Bf[ct][g][0], b1 = Bf[ct][g][1];
        i32x8 B0 = (i32x8){(int)b0.x, (int)b0.y, (int)b0.z, (int)b0.w, 0, 0, 0, 0};
        i32x8 B1 = (i32x8){(int)b1.x, (int)b1.y, (int)b1.z, (int)b1.w, 0, 0, 0, 0};
        f32x4 z4 = (f32x4){0.f, 0.f, 0.f, 0.f};
        z4 = __builtin_amdgcn_mfma_scale_f32_16x16x128_f8f6f4(
            A0, B0, z4, 4, 4, 0, SCA, 0, SCB);
        z4 = __builtin_amdgcn_mfma_scale_f32_16x16x128_f8f6f4(
            A1, B1, z4, 4, 4, 0, SCA, 0, SCB);
        acc[ct][g] = z4;
      }
    bool hi = (myct != 0);
    float vi = (hi ? acc[1][0][0] : acc[0][0][0]) + bf2f((u16)gq);
    float vf = (hi ? acc[1][1][0] : acc[0][1][0]) + bf2f((u16)(gq >> 16));
    float vg = (hi ? acc[1][2][0] : acc[0][2][0]) + bf2f((u16)(gq >> 32));
    float vo = (hi ? acc[1][3][0] : acc[0][3][0]) + bf2f((u16)(gq >> 48));
    cc = sgm(vf) * cc + sgm(vi) * thh(vg);
    float h = sgm(vo) * thh(cc);
    u32 nib = enc4(h * 4.f);                  // h scale 2^-2
    u32 nib2 = (u32)__shfl_xor((int)nib, 1);  // neighbor cell's nibble
    if ((quad & 1) == 0) {
      if ((c16 & 1) == 0)
        hq[cur ^ 1][mycell >> 1] = (unsigned char)(nib | (nib2 << 4));
      Hout[((size_t)b * 1024 + t) * 256 + mycell] = f2bf(h);
    }
    gq = ngq;
    cur ^= 1;
    __syncthreads();
  }
}

// ---------------- K6: fused output GEMM + log-softmax ------------------------
__global__ __launch_bounds__(256) void k_out(const u16* Hs, const float* enc,
                                             const u16* wlin, float* out) {
  __shared__ u16 As[64][40];
  __shared__ u16 Bs[128][40];
  const int m0 = blockIdx.x * 64;
  const int tid = threadIdx.x;
  const int srow = tid >> 2, sc8 = (tid & 3) * 8;
  const int brow = tid >> 1, bc16 = (tid & 1) * 16;
  const int w = tid >> 6, l = tid & 63;
  const int l15 = l & 15, lh = l >> 4;
  f32x4 acc[8] = {};
  for (int k0 = 0; k0 < KO_; k0 += 32) {
    int k = k0 + sc8;
    uint4 av;
    if (k < 256) {
      av = *(const uint4*)(Hs + (size_t)(m0 + srow) * 256 + k);
    } else {
      const float* src = enc + (size_t)(m0 + srow) * 512 + (k - 256);
      float4 f0 = *(const float4*)(src);
      float4 f1 = *(const float4*)(src + 4);
      av.x = pk2(f0.x, f0.y);
      av.y = pk2(f0.z, f0.w);
      av.z = pk2(f1.x, f1.y);
      av.w = pk2(f1.z, f1.w);
    }
    *(uint4*)&As[srow][sc8] = av;
    const u16* bsrc = wlin + (size_t)brow * KO_ + k0 + bc16;
    *(uint4*)&Bs[brow][bc16] = *(const uint4*)(bsrc);
    *(uint4*)&Bs[brow][bc16 + 8] = *(const uint4*)(bsrc + 8);
    __syncthreads();
    short8 a8 = *(const short8*)&As[16 * w + l15][lh * 8];
#pragma unroll
    for (int nt = 0; nt < 8; ++nt) {
      short8 b8 = *(const short8*)&Bs[nt * 16 + l15][lh * 8];
      acc[nt] = __builtin_amdgcn_mfma_f32_16x16x32_bf16(a8, b8, acc[nt], 0, 0, 0);
    }
    __syncthreads();
  }
#pragma unroll
  for (int r = 0; r < 4; ++r) {
    int gm = m0 + 16 * w + lh * 4 + r;
    float v[8];
#pragma unroll
    for (int nt = 0; nt < 8; ++nt) v[nt] = acc[nt][r];
    if ((gm & (T_ - 1)) == 0 && l15 == 1) v[0] = -1e10f;  // t==0, col==APP_ID
    float mx = v[0];
#pragma unroll
    for (int nt = 1; nt < 6; ++nt) mx = fmaxf(mx, v[nt]);
#pragma unroll
    for (int s = 1; s < 16; s <<= 1) mx = fmaxf(mx, __shfl_xor(mx, s));
    float s0 = 0.f;
#pragma unroll
    for (int nt = 0; nt < 6; ++nt)
      s0 += __builtin_amdgcn_exp2f(1.442695040888963f * (v[nt] - mx));
#pragma unroll
    for (int s = 1; s < 16; s <<= 1) s0 += __shfl_xor(s0, s);
    float lg = __builtin_amdgcn_logf(s0) * 0.6931471805599453f + mx;
#pragma unroll
    for (int nt = 0; nt < 6; ++nt)
      out[(size_t)gm * LBL_ + nt * 16 + l15] = v[nt] - lg;
  }
}

extern "C" void kernel_launch(void* const* d_in, const int* in_sizes, int n_in,
                              void* d_out, int out_size, void* d_ws, size_t ws_size,
                              hipStream_t stream) {
  const float* enc = (const float*)d_in[0];
  const float* ptab = (const float*)d_in[1];
  const float* Wih = (const float*)d_in[2];
  const float* bih = (const float*)d_in[3];
  const float* Whh = (const float*)d_in[4];
  const float* bhh = (const float*)d_in[5];
  const float* combW = (const float*)d_in[6];
  const float* combb = (const float*)d_in[7];
  const float* linW = (const float*)d_in[8];
  const int* pid = (const int*)d_in[9];
  const int* sidx = (const int*)d_in[10];

  char* ws = (char*)d_ws;
  size_t off = 0;
  auto alloc = [&](size_t bytes) {
    void* p = ws + off;
    off += (bytes + 255) & ~(size_t)255;
    return p;
  };
  // region1 (128MB): Pb (bf16, first 64MB) -> later aliased by G (bf16, 128MB)
  void* reg1 = alloc((size_t)B_ * T_ * G4_ * 2);
  u16* Xb = (u16*)alloc((size_t)T_ * B_ * KX_ * 2);  // -> aliased by H
  u16* Z = (u16*)alloc((size_t)T_ * B_ * HD_ * 2);   // S (2MB) lives here first
  u16* wc = (u16*)alloc(256 * KX_ * 2);
  u16* wih = (u16*)alloc(G4_ * HD_ * 2);
  u32* w4 = (u32*)alloc(G4_ * HD_ / 2);  // fp4 nibbles: 1024 x 128 B
  u16* wlin = (u16*)alloc(LPAD_ * KO_ * 2);
  float* biasg = (float*)alloc(G4_ * 4);
  u16* Pb = (u16*)reg1;
  u16* G = (u16*)reg1;
  u16* Hs = (u16*)Xb;
  float* S = (float*)Z;  // 1024*512 f32 = 2MB, dead before Z is written
  float* out = (float*)d_out;

  k_prep<<<2180, 256, 0, stream>>>(combW, Wih, bih, Whh, bhh, linW, wc, wih, w4,
                                   wlin, biasg);
  k_psum<<<B_ * 16, 512, 0, stream>>>(enc, S);
  k_pwrite<<<B_ * 16, 512, 0, stream>>>(enc, S, Pb);
  k_xbuild<<<T_ * B_ / 4, 320, 0, stream>>>(Pb, ptab, pid, sidx, Xb);
  dim3 g3(2, 512);
  k_gemm<0><<<g3, 256, 0, stream>>>(Xb, wc, combb, Z);
  dim3 g4(8, 512);
  k_gemm<1><<<g4, 256, 0, stream>>>(Z, wih, biasg, G);
  k_seq<<<B_, 512, 0, stream>>>(G, w4, Hs);
  k_out<<<1024, 256, 0, stream>>>(Hs, enc, wlin, out);
}